// Round 5
// baseline (272.421 us; speedup 1.0000x reference)
//
#include <hip/hip_runtime.h>

// LSTM B=8192,T=256,I=1,H=50 via MFMA -- R21 = R20 with FAST-MATH-SAFE
// packed-poly exp2 (R20 failed: absmax 0.129 == gates quantized to 2^k,
// i.e. the magic-number reduction kf=(x+MAG)-MAG was reassociated to x
// under the harness's fast-math; f collapsed to 0). Fix: range-reduce via
// __builtin_rintf (v_rndne_f32) -- not foldable -- and build 2^k from the
// cvt'd integer. Same cost (~13 instr / 26 cyc per pair vs 32 cyc for two
// hw v_exp_f32), deg-5 poly rel err 2.4e-6 << fp16 h quantization.
// Rationale (R17-R19 invariant): dur x VALUBusy ~= 94-97us across all
// structures -> VALU issue is the cost; trans = 78% of it. Cutting the 4
// gate exp2s (adjacent MFMA acc reg pairs -> v_pk_fma_f32 poly) trims
// chain 144 -> ~132 cyc. Ec + 2 rcps stay hw (serial, unpaired).
// Also kept from R20: x-wave prefetches x one FULL iteration ahead ->
// HBM latency off the barrier-pacer path.
// Math otherwise identical (R16 rcp-fused):
//   c2' = [c2*D2 + 2L*(Eg-1)*D1] * rcp(D1*D2),  D1=1+Ef, D2=(Eg+1)(1+Ei)
//   h   = (Ec-1) * rcp((Ec+1)(1+Eo)),           Ec=exp2(clamp(c2'))
// Structure (R12/R15): per block 16 batches; wave wv (0..12) owns tile T=wv;
// wave 13 = x-wave. Per step: D[208x16] = W[208x64] x h[64x16]; lane
// (lrow=ln&15, quad=ln>>4) of tile T holds gates (i,f,g,o) of (batch=lrow,
// unit=4T+quad) in its 4 acc regs. W single-product fp16, pre-scaled
// (sigmoid rows -log2e, g rows +2log2e) so gates feed exp2 directly.
// h fp16 plane, double-buffered, ONE barrier/step. Pad lanes redirect to
// slots 54/55. 2 blk/CU x 14 waves.

#define NTH 896
#define TST 256
#define MB 16
#define NBLK 512
#define HR 72            // h row stride in halfs (16B-aligned b128 frag reads)
#define HSZ (MB * HR)    // 1152 halfs per buffer

#define LOG2E 1.44269504088896f

typedef __attribute__((ext_vector_type(8))) _Float16 half8;
typedef __attribute__((ext_vector_type(4))) float float4v;
typedef __attribute__((ext_vector_type(2))) float f2;

__device__ __forceinline__ float rcp_(float v)  { return __builtin_amdgcn_rcpf(v); }
__device__ __forceinline__ float exp2_(float v) { return __builtin_amdgcn_exp2f(v); }
__device__ __forceinline__ unsigned short f16bits(float v) {
    _Float16 h = (_Float16)v;                 // RNE
    return *(unsigned short*)&h;
}

// exp2 of BOTH halves of a packed f32 pair. Range reduction via v_rndne
// (NOT the magic-add trick: that folds under fast-math reassociation --
// the R20 bug). Requires |x| < 126 (true: gates bounded ~25 in the log2
// domain; pad lanes have gate 0). Deg-5 Taylor of 2^f on f in [-.5,.5]:
// max rel err 2.4e-6. k->2^k via (k+127)<<23 int ops (exact).
__device__ __forceinline__ f2 exp2p(f2 x) {
    f2 kf;
    kf.x = __builtin_rintf(x.x);              // v_rndne_f32 (full-rate)
    kf.y = __builtin_rintf(x.y);
    const f2 f = x - kf;                      // exact, f in [-0.5, 0.5]
    const float C1 = 0.69314718056f, C2 = 0.24022650700f,
                C3 = 0.05550410866f, C4 = 0.00961812911f,
                C5 = 0.00133335581f;
    f2 p = (f2){C5, C5};
    p = __builtin_elementwise_fma(p, f, (f2){C4, C4});
    p = __builtin_elementwise_fma(p, f, (f2){C3, C3});
    p = __builtin_elementwise_fma(p, f, (f2){C2, C2});
    p = __builtin_elementwise_fma(p, f, (f2){C1, C1});
    p = __builtin_elementwise_fma(p, f, (f2){1.0f, 1.0f});
    const int e0 = ((int)kf.x + 127) << 23;   // float(2^k) bit pattern
    const int e1 = ((int)kf.y + 127) << 23;
    f2 s;
    s.x = __builtin_bit_cast(float, e0);
    s.y = __builtin_bit_cast(float, e1);
    return p * s;
}

__global__ __launch_bounds__(NTH, 7) void lstm_mfma(
    const float* __restrict__ x,      // [8192][256]
    const float* __restrict__ W_ih,   // [200]
    const float* __restrict__ W_hh,   // [200][50]
    const float* __restrict__ b_ih,   // [200]
    const float* __restrict__ b_hh,   // [200]
    const float* __restrict__ W_lin,  // [50]
    const float* __restrict__ b_lin,  // [1]
    float* __restrict__ out)          // [8192]
{
    __shared__ __align__(16) unsigned short Hh[2 * HSZ];   // fp16 h, double-buffered

    const int tid  = threadIdx.x;
    const int wv   = tid >> 6;      // 0..12 = tile T; 13 = x-wave
    const int ln   = tid & 63;
    const int lrow = ln & 15;       // batch-in-block / A-row m / D col
    const int quad = ln >> 4;
    const int bbase = (int)blockIdx.x * MB;
    const int T = wv;

    // ---- W-operand fragments (one tile per wave; one-time L2 reads).
    // Row gr=T*16+lrow -> unit j=gr>>2, gate g=gr&3, W row = g*50+j.
    // k = q2*32 + quad*8 + i; k=50 -> W_ih, k=51 -> bias; pad rows (j>=50)
    // zero (incl. wave 13 -- it never issues MFMA).
    // Pre-scale: sigmoid rows (g!=2) by -log2e, g rows by +2log2e.
    half8 wh[2];
    {
        const int gr = T * 16 + lrow;
        const int j  = gr >> 2, g = gr & 3;
        const int row = g * 50 + j;             // only dereferenced when j<50
        const float scl = (g == 2) ? (2.0f * LOG2E) : (-LOG2E);
        #pragma unroll
        for (int q2 = 0; q2 < 2; ++q2) {
            half8 h8;
            #pragma unroll
            for (int i = 0; i < 8; ++i) {
                const int k = q2 * 32 + quad * 8 + i;
                float V = 0.0f;
                if (j < 50) {
                    if (k < 50)       V = W_hh[row * 50 + k];
                    else if (k == 50) V = W_ih[row];
                    else if (k == 51) V = b_ih[row] + b_hh[row];
                }
                h8[i] = (_Float16)(V * scl);    // single fp16 product (RNE)
            }
            wh[q2] = h8;
        }
    }

    // ---- init h: zeros both bufs; k=50 buf0 <- fp16(x(b,0)); k=51 <- 1.0 both
    for (int i = tid; i < HSZ; i += NTH)       // HSZ uints = 2*HSZ halfs
        ((unsigned int*)Hh)[i] = 0u;
    __syncthreads();
    if (tid < MB) {
        float xv = x[(bbase + tid) * TST + 0];
        Hh[tid * HR + 50] = f16bits(xv);
        Hh[tid * HR + 51] = 0x3C00;            // fp16(1.0), never rewritten
        Hh[HSZ + tid * HR + 51] = 0x3C00;
    }
    __syncthreads();

    float c2 = 0.0f;                           // c in the x2log2e domain
    const unsigned short* Hr = &Hh[lrow * HR + quad * 8];  // frag read base
    int jw = T * 4 + quad;                                 // unit this lane writes
    if (jw >= 50) jw = 52 + quad;                          // pad redirect (54/55)
    unsigned short* Hw = &Hh[lrow * HR + jw];              // write base (hoisted)
    const float* xr = &x[(bbase + lrow) * TST];            // x-wave read row
    const float4v z4 = {0.f, 0.f, 0.f, 0.f};               // zero C operand

    // ---- x-wave prefetch-ahead registers: values for iteration t2 are
    // loaded during iteration t2-1 (prologue covers t2=0).
    float pA = 0.0f, pB = 0.0f;
    if (wv == 13) { pA = xr[1]; pB = xr[2]; }

    // one compute step; roff/woff compile-time after inlining -> imm offsets
    auto step1 = [&](int roff, int woff) {
        const half8 b0 = *(const half8*)(Hr + roff);
        const half8 b1 = *(const half8*)(Hr + roff + 32);

        float4v a4;
        a4 = __builtin_amdgcn_mfma_f32_16x16x32_f16(wh[0], b0, z4, 0, 0, 0);
        a4 = __builtin_amdgcn_mfma_f32_16x16x32_f16(wh[1], b1, a4, 0, 0, 0);

        // a4 = (ai,af,ag,ao): i/f/o pre-scaled by -L, g by +2L.
        // Acc regs are adjacent -> two packed-poly exp2 pairs.
        f2 g01; g01.x = a4[0]; g01.y = a4[1];
        f2 g23; g23.x = a4[2]; g23.y = a4[3];
        const f2 P1 = exp2p(g01);              // {Ei, Ef}
        const f2 P2 = exp2p(g23);              // {Eg, Eo}
        const f2 Q1 = P1 + 1.0f;               // {1+Ei, D1}
        const f2 Q2 = P2 + 1.0f;               // {Eg+1, 1+Eo}
        // c2' = f*c2 + i*(2L*tanh_g) with ONE rcp:
        const float D2 = Q2.x * Q1.x;
        const float R  = rcp_(Q1.y * D2);
        const float tg = (P2.x - 1.0f) * Q1.y;
        const float nm = fmaf(2.0f * LOG2E, tg, c2 * D2);
        c2 = fminf(nm * R, 120.0f);            // clamp: exp2 overflow guard
        // h = tanh(c)*sigmoid(ao) with ONE rcp:
        const float Ec = exp2_(c2);
        const float R2 = rcp_((Ec + 1.0f) * Q2.y);
        const float hn = (Ec - 1.0f) * R2;

        Hw[woff] = f16bits(hn);                // unconditional (pad-redirected)
    };

    #pragma unroll 1
    for (int t2 = 0; t2 < TST / 2; ++t2) {
        if (wv == 13) {
            // x-wave: issue NEXT iteration's loads, publish THIS iteration's
            // (prefetched last iter -> no vmcnt wait before the barriers).
            const float nA = xr[(2 * t2 + 3) & 255];   // t2=126/127: wrap, junk
            const float nB = xr[(2 * t2 + 4) & 255];   //   slots never read
            if (ln < 16)
                Hh[HSZ + lrow * HR + 50] = f16bits(pA);   // buf1 <- x(odd step)
            __syncthreads();                   // barrier 1 (even step done)
            if (ln < 16)
                Hh[lrow * HR + 50] = f16bits(pB);         // buf0 <- x(even step)
            __syncthreads();                   // barrier 2 (odd step done)
            pA = nA; pB = nB;
        } else {
            step1(0, HSZ);                     // even: read buf0, write buf1
            __syncthreads();
            step1(HSZ, 0);                     // odd:  read buf1, write buf0
            __syncthreads();
        }
    }

    // ---- epilogue: final h in buf 0 (t=255 wrote buf0)
    if (tid < MB) {
        float s = b_lin[0];
        #pragma unroll 10
        for (int k = 0; k < 50; ++k) {
            float hk = (float)(*(const _Float16*)&Hh[tid * HR + k]);
            s += hk * W_lin[k];
        }
        out[bbase + tid] = s;
    }
}

extern "C" void kernel_launch(void* const* d_in, const int* in_sizes, int n_in,
                              void* d_out, int out_size, void* d_ws, size_t ws_size,
                              hipStream_t stream) {
    const float* x     = (const float*)d_in[0];
    const float* W_ih  = (const float*)d_in[1];
    const float* W_hh  = (const float*)d_in[2];
    const float* b_ih  = (const float*)d_in[3];
    const float* b_hh  = (const float*)d_in[4];
    const float* W_lin = (const float*)d_in[5];
    const float* b_lin = (const float*)d_in[6];
    float* out = (float*)d_out;

    lstm_mfma<<<dim3(NBLK), dim3(NTH), 0, stream>>>(
        x, W_ih, W_hh, b_ih, b_hh, W_lin, b_lin, out);
}

// Round 6
// 210.875 us; speedup vs baseline: 1.2919x; 1.2919x over previous
//
#include <hip/hip_runtime.h>

// LSTM B=8192,T=256,I=1,H=50 via MFMA -- R22 = R16 champion (161us) +
// PARITY-BALANCED SIMD LOAD + x-prefetch-ahead.
// R21 post-mortem: packed-poly exp2 scalarized (dur x VALUBusy 97->145
// us-equiv) -- trans substitution is DEAD; 7 quarter-rate ops/chain is the
// floor. New per-SIMD fit of R16's 1512-cyc step: wave->SIMD = wv%4; 13
// heavy chain-waves + 1 light x-wave -> SIMD0 gets 4 heavy ({0,4,8,12}),
// others 3. Two phase-locked blocks double it: SIMD0 = 8 chains x 144cyc
// = 1152 issue; wall = 1152 + act latency ~230 + barrier ~= 1500 == 1512
// measured. Fix: 13 mod 4 always leaves one 4-heavy SIMD, but WHICH is
// chooseable by where the x-wave sits (wv13->SIMD1 or wv12->SIMD0). Key on
// block parity ((b>>8)^b)&1 (covers (b,b+256) and (2b,2b+1) pairings):
// even blocks -> 4-heavy on SIMD0, odd -> SIMD1; combined (7,7,6,6) vs
// (8,6,6,6). Max-SIMD issue 1152->1008 (-12.5%).
// Also kept (verified passing in R21): x-wave prefetches x one FULL
// iteration ahead -> HBM latency off the barrier-pacer path.
// Math (R16, rcp-fused, 7 quarter-rate ops/lane/step, bit-identical):
//   c2' = [c2*D2 + 2L*(Eg-1)*D1] * rcp(D1*D2),  D1=1+Ef, D2=(Eg+1)(1+Ei)
//   h   = (Ec-1) * rcp((Ec+1)(1+Eo)),           Ec=exp2(clamp(c2'))
// Structure (R12/R15): per block 16 batches; 13 compute waves own tiles
// 0..12; 1 x-wave owns the k=50 x-column. Per step: D[208x16] =
// W[208x64] x h[64x16]; lane (lrow=ln&15, quad=ln>>4) of tile T holds
// gates (i,f,g,o) of (batch=lrow, unit=4T+quad) in its 4 acc regs. W
// single-product fp16, pre-scaled (sigmoid rows -log2e, g rows +2log2e)
// so gates feed exp2 directly. h fp16 plane, double-buffered, ONE
// barrier/step. Pad lanes redirect to slots 54/55. 2 blk/CU x 14 waves.

#define NTH 896
#define TST 256
#define MB 16
#define NBLK 512
#define HR 72            // h row stride in halfs (16B-aligned b128 frag reads)
#define HSZ (MB * HR)    // 1152 halfs per buffer

#define LOG2E 1.44269504088896f

typedef __attribute__((ext_vector_type(8))) _Float16 half8;
typedef __attribute__((ext_vector_type(4))) float float4v;

__device__ __forceinline__ float rcp_(float v)  { return __builtin_amdgcn_rcpf(v); }
__device__ __forceinline__ float exp2_(float v) { return __builtin_amdgcn_exp2f(v); }
__device__ __forceinline__ unsigned short f16bits(float v) {
    _Float16 h = (_Float16)v;                 // RNE
    return *(unsigned short*)&h;
}

__global__ __launch_bounds__(NTH, 7) void lstm_mfma(
    const float* __restrict__ x,      // [8192][256]
    const float* __restrict__ W_ih,   // [200]
    const float* __restrict__ W_hh,   // [200][50]
    const float* __restrict__ b_ih,   // [200]
    const float* __restrict__ b_hh,   // [200]
    const float* __restrict__ W_lin,  // [50]
    const float* __restrict__ b_lin,  // [1]
    float* __restrict__ out)          // [8192]
{
    __shared__ __align__(16) unsigned short Hh[2 * HSZ];   // fp16 h, double-buffered

    const int tid  = threadIdx.x;
    const int wv   = tid >> 6;      // 14 waves
    const int ln   = tid & 63;
    const int lrow = ln & 15;       // batch-in-block / A-row m / D col
    const int quad = ln >> 4;
    const int bbase = (int)blockIdx.x * MB;

    // ---- parity-keyed x-wave placement: even blocks x at wv13 (SIMD1,
    // 4-heavy SIMD0); odd blocks x at wv12 (SIMD0, 4-heavy SIMD1).
    const int par = (((int)blockIdx.x >> 8) ^ (int)blockIdx.x) & 1;
    const int xw  = 13 - par;                  // x-duty wave id
    const bool isx = (wv == xw);
    // non-x waves cover tiles 0..12 exactly once; x-wave gets T=13 (all-pad)
    const int T = isx ? 13 : ((wv < xw) ? wv : 12);

    // ---- W-operand fragments (one tile per wave; one-time L2 reads).
    // Row gr=T*16+lrow -> unit j=gr>>2, gate g=gr&3, W row = g*50+j.
    // k = q2*32 + quad*8 + i; k=50 -> W_ih, k=51 -> bias; pad rows (j>=50)
    // zero (incl. the x-wave via T=13 -- it never issues MFMA anyway).
    // Pre-scale: sigmoid rows (g!=2) by -log2e, g rows by +2log2e.
    half8 wh[2];
    {
        const int gr = T * 16 + lrow;
        const int j  = gr >> 2, g = gr & 3;
        const int row = g * 50 + j;             // only dereferenced when j<50
        const float scl = (g == 2) ? (2.0f * LOG2E) : (-LOG2E);
        #pragma unroll
        for (int q2 = 0; q2 < 2; ++q2) {
            half8 h8;
            #pragma unroll
            for (int i = 0; i < 8; ++i) {
                const int k = q2 * 32 + quad * 8 + i;
                float V = 0.0f;
                if (j < 50) {
                    if (k < 50)       V = W_hh[row * 50 + k];
                    else if (k == 50) V = W_ih[row];
                    else if (k == 51) V = b_ih[row] + b_hh[row];
                }
                h8[i] = (_Float16)(V * scl);    // single fp16 product (RNE)
            }
            wh[q2] = h8;
        }
    }

    // ---- init h: zeros both bufs; k=50 buf0 <- fp16(x(b,0)); k=51 <- 1.0 both
    for (int i = tid; i < HSZ; i += NTH)       // HSZ uints = 2*HSZ halfs
        ((unsigned int*)Hh)[i] = 0u;
    __syncthreads();
    if (tid < MB) {
        float xv = x[(bbase + tid) * TST + 0];
        Hh[tid * HR + 50] = f16bits(xv);
        Hh[tid * HR + 51] = 0x3C00;            // fp16(1.0), never rewritten
        Hh[HSZ + tid * HR + 51] = 0x3C00;
    }
    __syncthreads();

    float c2 = 0.0f;                           // c in the x2log2e domain
    const unsigned short* Hr = &Hh[lrow * HR + quad * 8];  // frag read base
    int jw = T * 4 + quad;                                 // unit this lane writes
    if (jw >= 50) jw = 52 + quad;                          // pad redirect (54/55)
    unsigned short* Hw = &Hh[lrow * HR + jw];              // write base (hoisted)
    const float* xr = &x[(bbase + lrow) * TST];            // x-wave read row
    const float4v z4 = {0.f, 0.f, 0.f, 0.f};               // zero C operand

    // ---- x-wave prefetch-ahead registers: values for iteration t2 are
    // loaded during iteration t2-1 (prologue covers t2=0).
    float pA = 0.0f, pB = 0.0f;
    if (isx) { pA = xr[1]; pB = xr[2]; }

    // one compute step; roff/woff compile-time after inlining -> imm offsets
    auto step1 = [&](int roff, int woff) {
        const half8 b0 = *(const half8*)(Hr + roff);
        const half8 b1 = *(const half8*)(Hr + roff + 32);

        float4v a4;
        a4 = __builtin_amdgcn_mfma_f32_16x16x32_f16(wh[0], b0, z4, 0, 0, 0);
        a4 = __builtin_amdgcn_mfma_f32_16x16x32_f16(wh[1], b1, a4, 0, 0, 0);

        // a4 = (ai,af,ag,ao): i/f/o pre-scaled by -L, g by +2L.
        const float Ei = exp2_(a4[0]);
        const float Ef = exp2_(a4[1]);
        const float Eg = exp2_(a4[2]);
        const float Eo = exp2_(a4[3]);
        // c2' = f*c2 + i*(2L*tanh_g) with ONE rcp:
        const float D1 = 1.0f + Ef;
        const float D2 = (Eg + 1.0f) * (1.0f + Ei);
        const float R  = rcp_(D1 * D2);
        const float tg = (Eg - 1.0f) * D1;
        const float nm = fmaf(2.0f * LOG2E, tg, c2 * D2);
        c2 = fminf(nm * R, 120.0f);            // clamp: exp2 overflow guard
        // h = tanh(c)*sigmoid(ao) with ONE rcp:
        const float Ec = exp2_(c2);
        const float R2 = rcp_((Ec + 1.0f) * (1.0f + Eo));
        const float hn = (Ec - 1.0f) * R2;

        Hw[woff] = f16bits(hn);                // unconditional (pad-redirected)
    };

    #pragma unroll 1
    for (int t2 = 0; t2 < TST / 2; ++t2) {
        if (isx) {
            // x-wave: issue NEXT iteration's loads, publish THIS iteration's
            // (prefetched last iter -> no vmcnt wait before the barriers).
            const float nA = xr[(2 * t2 + 3) & 255];   // t2=126/127: wrap, junk
            const float nB = xr[(2 * t2 + 4) & 255];   //   slots never read
            if (ln < 16)
                Hh[HSZ + lrow * HR + 50] = f16bits(pA);   // buf1 <- x(odd step)
            __syncthreads();                   // barrier 1 (even step done)
            if (ln < 16)
                Hh[lrow * HR + 50] = f16bits(pB);         // buf0 <- x(even step)
            __syncthreads();                   // barrier 2 (odd step done)
            pA = nA; pB = nB;
        } else {
            step1(0, HSZ);                     // even: read buf0, write buf1
            __syncthreads();
            step1(HSZ, 0);                     // odd:  read buf1, write buf0
            __syncthreads();
        }
    }

    // ---- epilogue: final h in buf 0 (t=255 wrote buf0)
    if (tid < MB) {
        float s = b_lin[0];
        #pragma unroll 10
        for (int k = 0; k < 50; ++k) {
            float hk = (float)(*(const _Float16*)&Hh[tid * HR + k]);
            s += hk * W_lin[k];
        }
        out[bbase + tid] = s;
    }
}

extern "C" void kernel_launch(void* const* d_in, const int* in_sizes, int n_in,
                              void* d_out, int out_size, void* d_ws, size_t ws_size,
                              hipStream_t stream) {
    const float* x     = (const float*)d_in[0];
    const float* W_ih  = (const float*)d_in[1];
    const float* W_hh  = (const float*)d_in[2];
    const float* b_ih  = (const float*)d_in[3];
    const float* b_hh  = (const float*)d_in[4];
    const float* W_lin = (const float*)d_in[5];
    const float* b_lin = (const float*)d_in[6];
    float* out = (float*)d_out;

    lstm_mfma<<<dim3(NBLK), dim3(NTH), 0, stream>>>(
        x, W_ih, W_hh, b_ih, b_hh, W_lin, b_lin, out);
}